// Round 9
// baseline (189.405 us; speedup 1.0000x reference)
//
#include <hip/hip_runtime.h>

// CharGRU2: 2-layer GRU (reset_after=true) + dense + softmax, fp32.
// B=2048, T=128, V=256, H=20, L=15.
//
// Round 21 = R16 (best: 55.7us — exp2 pre-scaled gates, parallel DPP hops,
// rec1 dot mid-iteration, cross-layer software pipeline, 2 waves/SIMD) with
// both LDS h round trips replaced by ds_bpermute REGISTER broadcast:
//
//  R16's residual non-ALU cost: 2x (ds_write -> fence -> 5x ds_read_b128)
//  per iter, ~120+cy latency each, only partially hidden, plus write->read
//  ordering. ds_bpermute reads the SOURCE LANE's register directly: no LDS
//  allocation, no store ordering, no VALU->SGPR hazard (the R15 readlane
//  trap), outputs stay in VGPRs and feed full-rate scalar v_fmac chains
//  (R19 lesson: packed fp32 is half-rate/element, so scalar fma == pk fma
//  in ALU cycles; scalar needs no {x,y} marshalling).
//  - 20 broadcast addresses (home-lane*4) preloaded in pinned VGPRs.
//  - bp0 (h0_t) consumed after DOT2 + L1 gates (~150cy gap); bp1 (h1_t)
//    consumed NEXT iteration in DOT2 (~300cy gap) — bpermute latency
//    fully hidden, 20-deep issue pipelines in the DS unit alongside VALU.
//  - zero LDS; dense epilogue reads h1 from bp1 registers.
//
//  Failed-experiment ledger (do not retry): R13 s_sleep stagger (null),
//  R14/15 readlane->SGPR dots (-29%), R17 1 wave/SIMD 2-batch ILP (-24%),
//  R18 barrier-synced layer split (-31%), R19 asm pk_fma + unroll4 (-17%),
//  R20 flag-synced producer/consumer (-19%).
//
// Layout recap: lane 16r+3u+p owns gate column p*20+(5r+u) (p=0:z 1:r 2:h~);
// home lane of unit j = 16*(j/5)+3*(j%5)+2; lane 16r+15 dups pos 14. Gate
// hops never cross a 16-lane DPP row.

#define BB 2048
#define TT 128
#define HH 20
#define LL 15
#define H3 60

#if __has_builtin(__builtin_amdgcn_exp2f)
#define EXP2(x) __builtin_amdgcn_exp2f(x)
#else
#define EXP2(x) exp2f(x)
#endif

__device__ __forceinline__ float bclane(float v, int k) {
    return __int_as_float(__builtin_amdgcn_readlane(__float_as_int(v), k));
}
__device__ __forceinline__ float bperm(int addr, float v) {
    return __int_as_float(__builtin_amdgcn_ds_bpermute(addr, __float_as_int(v)));
}
__device__ __forceinline__ float dpp_rshr1(float v) {
    return __int_as_float(__builtin_amdgcn_update_dpp(
        0, __float_as_int(v), 0x111, 0xF, 0xF, true));
}
__device__ __forceinline__ float dpp_rshr2(float v) {
    return __int_as_float(__builtin_amdgcn_update_dpp(
        0, __float_as_int(v), 0x112, 0xF, 0xF, true));
}
__device__ __forceinline__ float fast_rcp(float x) { return __builtin_amdgcn_rcpf(x); }
#define PIN(v) asm volatile("" : "+v"(v))

extern "C" __global__ __launch_bounds__(256)
__attribute__((amdgpu_waves_per_eu(2, 2)))
void gru2_kernel(const int* __restrict__ x, const float* __restrict__ W0,
                 const float* __restrict__ U0, const float* __restrict__ b0i,
                 const float* __restrict__ b0r, const float* __restrict__ W1,
                 const float* __restrict__ U1, const float* __restrict__ b1i,
                 const float* __restrict__ b1r, const float* __restrict__ Wd,
                 const float* __restrict__ bd, float* __restrict__ out)
{
    const int lane = threadIdx.x & 63;
    const int w = threadIdx.x >> 6;
    const int b = blockIdx.x * 4 + w;                    // batch = wave id
    const int row = lane >> 4;                           // DPP row 0..3
    const int pos = lane & 15;                           // pos in row
    const int pc  = (pos < 15) ? pos : 14;               // lane 16r+15 dups pos 14
    const int u   = pc / 3;                              // unit-in-row 0..4
    const int p3  = pc % 3;                              // 0:z 1:r 2:h~
    const int j   = row * 5 + u;                         // unit 0..19
    const int col = p3 * 20 + j;                         // owned gate column
    (void)j;

    // exp2 gate scale: z/r columns -log2e, h~ columns -2log2e
    const float gsc = (p3 == 2) ? -2.8853900817779268f : -1.4426950408889634f;

    // ---- broadcast addresses: home lane of unit k, in bytes, pinned ----
    int bpa[HH];
#pragma unroll
    for (int k = 0; k < HH; ++k)
        bpa[k] = ((((k / 5) << 4) + (k % 5) * 3 + 2) << 2);
#pragma unroll
    for (int k = 0; k < HH; ++k) PIN(bpa[k]);

    // ---- weight columns (scalar, pre-scaled) into VGPRs, pinned ----
    float u0c[HH], w1c[HH], u1c[HH];
#pragma unroll
    for (int k = 0; k < HH; ++k) {
        u0c[k] = U0[k * H3 + col] * gsc;
        w1c[k] = W1[k * H3 + col] * gsc;
        u1c[k] = U1[k * H3 + col] * gsc;
    }
#pragma unroll
    for (int k = 0; k < HH; ++k) { PIN(u0c[k]); PIN(w1c[k]); PIN(u1c[k]); }
    const float bi0 = b0i[col] * gsc, br0 = b0r[col] * gsc;
    const float bi1 = b1i[col] * gsc, br1 = b1r[col] * gsc;

    // ---- tokens ----
    const int* xrow = x + b * TT;
    const int tokA = xrow[lane];
    const int tokB = xrow[64 + lane];

    float h0 = 0.f, h1 = 0.f;                            // home lanes hold state

    // ---- W0 pipeline: row t ready(scaled), row t+1 raw, token t+2 staged ----
    const int tok0 = __builtin_amdgcn_readlane(tokA, 0);
    const int tok1 = __builtin_amdgcn_readlane(tokA, 1);
    int tokn2 = __builtin_amdgcn_readlane(tokA, 2);
    float xw_cur = fmaf(W0[tok0 * H3 + col], gsc, bi0);
    float xw_nxt = W0[tok1 * H3 + col];                  // raw

    float bp0[HH], bp1[HH];                              // broadcast h0 / h1
#pragma unroll
    for (int k = 0; k < HH; ++k) bp1[k] = 0.f;           // h1_{-1} = 0
    float rec0, xw1, rec1;                               // carried dot results

    // broadcast H into BP via ds_bpermute (DS pipe, overlaps VALU)
#define BCAST(H, BP)                                                          \
    _Pragma("unroll")                                                         \
    for (int k = 0; k < HH; ++k) BP[k] = bperm(bpa[k], H);

    // dots from bp0 (=h0_t): rec0 (U0) + xw1 (W1), 2 chains each
#define DOT01()                                                               \
    {                                                                         \
        float a0 = br0, e0 = 0.f, a1 = bi1, e1 = 0.f;                         \
        _Pragma("unroll")                                                     \
        for (int k = 0; k < HH / 2; ++k) {                                    \
            a0 = fmaf(bp0[2 * k],     u0c[2 * k],     a0);                    \
            e0 = fmaf(bp0[2 * k + 1], u0c[2 * k + 1], e0);                    \
            a1 = fmaf(bp0[2 * k],     w1c[2 * k],     a1);                    \
            e1 = fmaf(bp0[2 * k + 1], w1c[2 * k + 1], e1);                    \
        }                                                                     \
        rec0 = a0 + e0; xw1 = a1 + e1;                                        \
    }
    // dot from bp1 (=h1_{t-1}): rec1 (U1)
#define DOT2()                                                                \
    {                                                                         \
        float a2 = br1, e2 = 0.f;                                             \
        _Pragma("unroll")                                                     \
        for (int k = 0; k < HH / 2; ++k) {                                    \
            a2 = fmaf(bp1[2 * k],     u1c[2 * k],     a2);                    \
            e2 = fmaf(bp1[2 * k + 1], u1c[2 * k + 1], e2);                    \
        }                                                                     \
        rec1 = a2 + e2;                                                       \
    }
    // gate block: one exp2/rcp stream serves z,r (sigmoid) and h~ (tanh)
#define GATES(XW, REC, H)                                                     \
    {                                                                         \
        const float e_  = EXP2((XW) + (REC));                                 \
        const float t_  = fast_rcp(1.f + e_);                                 \
        const float rv_ = dpp_rshr1(t_);                                      \
        const float zv_ = dpp_rshr2(t_);                                      \
        const float eh_ = EXP2(fmaf(rv_, (REC), (XW)));                       \
        const float th_ = fast_rcp(1.f + eh_);                                \
        const float hh_ = fmaf(2.f, th_, -1.f);                               \
        H = fmaf(zv_, (H) - hh_, hh_);                                        \
    }

    // ---- prologue: L0 for t=0 (h0_{-1}=0 -> rec0 = br0) ----
    {
        const float pf = W0[tokn2 * H3 + col];
        const int tokn3 = __builtin_amdgcn_readlane(tokA, 3);
        GATES(xw_cur, br0, h0);
        BCAST(h0, bp0);
        xw_cur = fmaf(xw_nxt, gsc, bi0); xw_nxt = pf; tokn2 = tokn3;
        DOT01();                                         // rec0/xw1 for i=1
    }

    // ---- main loop: i = 1..127 — L0 gates / bcast / rec1 dot / L1 gates /
    //      bcast / rotate / tail dots ----
#pragma unroll 2
    for (int i = 1; i < TT; ++i) {
        const int t3 = (i + 3 < TT) ? (i + 3) : (TT - 1);
        const float pf = W0[tokn2 * H3 + col];
        const int tokn3 = __builtin_amdgcn_readlane(t3 < 64 ? tokA : tokB, t3 & 63);

        // ---- L0 gates (t=i): rec0/xw_cur carried, chain starts now ----
        GATES(xw_cur, rec0, h0);
        BCAST(h0, bp0);                                  // DS pipe, hidden

        // ---- rec1 dot: bp1 broadcast one full iteration ago ----
        DOT2();

        // ---- L1 gates (t=i-1) ----
        GATES(xw1, rec1, h1);
        BCAST(h1, bp1);                                  // consumed next iter

        // rotate W0 pipeline (scale applied here: fma, not add)
        xw_cur = fmaf(xw_nxt, gsc, bi0); xw_nxt = pf; tokn2 = tokn3;

        // ---- tail dots for i+1: consume bp0 (gap = DOT2 + L1 gates) ----
        DOT01();
    }

    // ---- epilogue: L1 for t=127 (xw1 carried; rec1 from final bp1) ----
    {
        DOT2();
        GATES(xw1, rec1, h1);
        BCAST(h1, bp1);                                  // final h1, all lanes
    }

    // ---- dense (h1 @ Wd + bd) + softmax, lanes 0..14, no LDS ----
    const int l = lane < LL ? lane : LL - 1;
    float acc = bd[l];
#pragma unroll
    for (int k = 0; k < HH; ++k)
        acc = fmaf(bp1[k], Wd[k * LL + l], acc);         // register h1

    float m = acc;
#pragma unroll
    for (int i = 0; i < LL; ++i) m = fmaxf(m, bclane(acc, i));
    const float e = __expf(acc - m);
    float s = 0.f;
#pragma unroll
    for (int i = 0; i < LL; ++i) s += bclane(e, i);
    const float pr = e * fast_rcp(s);

    if (lane < LL) out[b * LL + lane] = pr;
}

extern "C" void kernel_launch(void* const* d_in, const int* in_sizes, int n_in,
                              void* d_out, int out_size, void* d_ws, size_t ws_size,
                              hipStream_t stream) {
    const int*   x   = (const int*)  d_in[0];
    const float* W0  = (const float*)d_in[1];
    const float* U0  = (const float*)d_in[2];
    const float* b0i = (const float*)d_in[3];
    const float* b0r = (const float*)d_in[4];
    const float* W1  = (const float*)d_in[5];
    const float* U1  = (const float*)d_in[6];
    const float* b1i = (const float*)d_in[7];
    const float* b1r = (const float*)d_in[8];
    const float* Wd  = (const float*)d_in[9];
    const float* bd  = (const float*)d_in[10];
    // d_in[11] = drop_rate (identity), unused
    float* out = (float*)d_out;

    // 1 batch/wave, 4 waves/block -> 512 blocks = 2 blocks/CU = 2 waves/SIMD.
    dim3 grid(BB / 4), block(256);
    hipLaunchKernelGGL(gru2_kernel, grid, block, 0, stream,
                       x, W0, U0, b0i, b0r, W1, U1, b1i, b1r, Wd, bd, out);
}

// Round 11
// 124.090 us; speedup vs baseline: 1.5264x; 1.5264x over previous
//
#include <hip/hip_runtime.h>

// CharGRU2: 2-layer GRU (reset_after=true) + dense + softmax, fp32.
// B=2048, T=128, V=256, H=20, L=15.
//
// Round 23 = R16 (champion: 55.7us) + the two SAFE levers from R22:
//
//  1. s_setprio(1) AROUND GATE CHAINS (T5): the 2 waves/SIMD are fully
//     independent (different batches, no barriers) — the measured +4-7%
//     setprio regime. A wave in its latency-critical gate chain gets issue
//     preference; the co-wave's dot instructions fill the holes.
//  2. TOKEN LOOP SPLIT at the tokA/tokB boundary (i<=60 / 61..124 /
//     125..127): kills the per-iter v_cmp + v_cndmask + &63.
//
//  R22 LESSON (correctness): the per-h-store LDSFENCE is LOAD-BEARING.
//  The scalar float ds_write and float4 ds_read are differently-typed LDS
//  accesses whose real dependency is CROSS-LANE; without the "memory"
//  fence, TBAA lets the scheduler hoist ds_read_b128 above the ds_write
//  (absmax 7.3e-3). Fences restored at exactly R16's placement.
//
//  Falsified structures (do not retry): R13 s_sleep stagger (null), R14/15
//  readlane->SGPR dots (-29%), R17 1 wave/SIMD 2-batch ILP (-24%), R18
//  barrier-synced layer split (-31%), R19 asm pk_fma + unroll4 (-17%; pk
//  fp32 is half-rate per element), R20 flag-synced P/C (-19%), R21
//  ds_bpermute broadcast (-124%: DS-pipe serialization), R22 fence removal
//  (WRONG RESULTS).
//
// Layout recap: lane 16r+3u+p owns gate column p*20+(5r+u) (p=0:z 1:r 2:h~);
// home lane of unit j = 16*(j/5)+3*(j%5)+2; lane 16r+15 dups pos 14 and is
// excluded from LDS writes. Gate hops never cross a 16-lane DPP row.

#define BB 2048
#define TT 128
#define HH 20
#define LL 15
#define H3 60

typedef float v2f __attribute__((ext_vector_type(2)));

#if __has_builtin(__builtin_amdgcn_exp2f)
#define EXP2(x) __builtin_amdgcn_exp2f(x)
#else
#define EXP2(x) exp2f(x)
#endif

__device__ __forceinline__ float bclane(float v, int k) {
    return __int_as_float(__builtin_amdgcn_readlane(__float_as_int(v), k));
}
__device__ __forceinline__ float dpp_rshr1(float v) {
    return __int_as_float(__builtin_amdgcn_update_dpp(
        0, __float_as_int(v), 0x111, 0xF, 0xF, true));
}
__device__ __forceinline__ float dpp_rshr2(float v) {
    return __int_as_float(__builtin_amdgcn_update_dpp(
        0, __float_as_int(v), 0x112, 0xF, 0xF, true));
}
__device__ __forceinline__ float fast_rcp(float x) { return __builtin_amdgcn_rcpf(x); }
#define PIN(v) asm volatile("" : "+v"(v))
#define LDSFENCE() asm volatile("" ::: "memory")

extern "C" __global__ __launch_bounds__(256)
__attribute__((amdgpu_waves_per_eu(2, 2)))
void gru2_kernel(const int* __restrict__ x, const float* __restrict__ W0,
                 const float* __restrict__ U0, const float* __restrict__ b0i,
                 const float* __restrict__ b0r, const float* __restrict__ W1,
                 const float* __restrict__ U1, const float* __restrict__ b1i,
                 const float* __restrict__ b1r, const float* __restrict__ Wd,
                 const float* __restrict__ bd, float* __restrict__ out)
{
    const int lane = threadIdx.x & 63;
    const int w = threadIdx.x >> 6;
    const int b = blockIdx.x * 4 + w;                    // batch = wave id
    const int row = lane >> 4;                           // DPP row 0..3
    const int pos = lane & 15;                           // pos in row
    const int pc  = (pos < 15) ? pos : 14;               // lane 16r+15 dups pos 14
    const int u   = pc / 3;                              // unit-in-row 0..4
    const int p3  = pc % 3;                              // 0:z 1:r 2:h~
    const int j   = row * 5 + u;                         // unit 0..19
    const bool home = (pos < 15) && (p3 == 2);           // 20 h-home lanes
    const int col = p3 * 20 + j;                         // owned gate column

    // exp2 gate scale: z/r columns -log2e, h~ columns -2log2e
    const float gsc = (p3 == 2) ? -2.8853900817779268f : -1.4426950408889634f;

    // per-wave LDS staging of h0/h1 (wave-uniform broadcast reads)
    __shared__ __align__(16) float hbuf[4][2][24];
    float* h0buf = &hbuf[w][0][0];
    float* h1buf = &hbuf[w][1][0];
    const float4* h0q = (const float4*)h0buf;
    const float4* h1q = (const float4*)h1buf;
    if (home) { h0buf[j] = 0.f; h1buf[j] = 0.f; }
    LDSFENCE();

    // ---- weight columns (k-pair packed, pre-scaled) into VGPRs, pinned ----
    v2f u0p[10], w1p[10], u1p[10];
#pragma unroll
    for (int q = 0; q < 10; ++q) {
        const int k0 = (2 * q) * H3, k1 = (2 * q + 1) * H3;
        u0p[q] = v2f{U0[k0 + col] * gsc, U0[k1 + col] * gsc};
        w1p[q] = v2f{W1[k0 + col] * gsc, W1[k1 + col] * gsc};
        u1p[q] = v2f{U1[k0 + col] * gsc, U1[k1 + col] * gsc};
    }
#pragma unroll
    for (int q = 0; q < 10; ++q) { PIN(u0p[q]); PIN(w1p[q]); PIN(u1p[q]); }
    float bi0 = b0i[col] * gsc, br0 = b0r[col] * gsc;
    float bi1 = b1i[col] * gsc, br1 = b1r[col] * gsc;
    PIN(bi0); PIN(br0); PIN(bi1); PIN(br1);

    // ---- tokens ----
    const int* xrow = x + b * TT;
    const int tokA = xrow[lane];
    const int tokB = xrow[64 + lane];

    float h0 = 0.f, h1 = 0.f;                            // home lanes hold state

    // ---- W0 pipeline: row t ready(scaled), row t+1 raw, token t+2 staged ----
    const int tok0 = __builtin_amdgcn_readlane(tokA, 0);
    const int tok1 = __builtin_amdgcn_readlane(tokA, 1);
    int tokn2 = __builtin_amdgcn_readlane(tokA, 2);
    float xw_cur = fmaf(W0[tok0 * H3 + col], gsc, bi0);
    float xw_nxt = W0[tok1 * H3 + col];                  // raw

    float4 c0[5], c1[5];                                 // register-staged h quads
    float rec0, xw1, rec1;                               // carried dot results

    // dots from c0 (=h0_t): rec0 (U0) + xw1 (W1), two 5-deep pk chains each
#define DOT01()                                                               \
    {                                                                         \
        v2f a0a = v2f{br0, 0.f}, a0b = v2f{0.f, 0.f};                         \
        v2f a1a = v2f{bi1, 0.f}, a1b = v2f{0.f, 0.f};                         \
        _Pragma("unroll")                                                     \
        for (int q = 0; q < 5; ++q) {                                         \
            const v2f hA = v2f{c0[q].x, c0[q].y}, hB = v2f{c0[q].z, c0[q].w}; \
            a0a = __builtin_elementwise_fma(hA, u0p[2 * q], a0a);             \
            a0b = __builtin_elementwise_fma(hB, u0p[2 * q + 1], a0b);         \
            a1a = __builtin_elementwise_fma(hA, w1p[2 * q], a1a);             \
            a1b = __builtin_elementwise_fma(hB, w1p[2 * q + 1], a1b);         \
        }                                                                     \
        { const v2f t = a0a + a0b; rec0 = t.x + t.y; }                        \
        { const v2f t = a1a + a1b; xw1  = t.x + t.y; }                        \
    }
    // dot from c1 (=h1_{t-1}): rec1 (U1)
#define DOT2()                                                                \
    {                                                                         \
        v2f a2a = v2f{br1, 0.f}, a2b = v2f{0.f, 0.f};                         \
        _Pragma("unroll")                                                     \
        for (int q = 0; q < 5; ++q) {                                         \
            const v2f gA = v2f{c1[q].x, c1[q].y}, gB = v2f{c1[q].z, c1[q].w}; \
            a2a = __builtin_elementwise_fma(gA, u1p[2 * q], a2a);             \
            a2b = __builtin_elementwise_fma(gB, u1p[2 * q + 1], a2b);         \
        }                                                                     \
        { const v2f t = a2a + a2b; rec1 = t.x + t.y; }                        \
    }
    // gate block: one exp2/rcp stream serves z,r (sigmoid) and h~ (tanh);
    // setprio(1) marks the latency-critical chain for the CU arbiter.
#define GATES(XW, REC, H)                                                     \
    {                                                                         \
        __builtin_amdgcn_s_setprio(1);                                        \
        const float e_  = EXP2((XW) + (REC));                                 \
        const float t_  = fast_rcp(1.f + e_);                                 \
        const float rv_ = dpp_rshr1(t_);                                      \
        const float zv_ = dpp_rshr2(t_);                                      \
        const float eh_ = EXP2(fmaf(rv_, (REC), (XW)));                       \
        const float th_ = fast_rcp(1.f + eh_);                                \
        const float hh_ = fmaf(2.f, th_, -1.f);                               \
        H = fmaf(zv_, (H) - hh_, hh_);                                        \
        __builtin_amdgcn_s_setprio(0);                                        \
    }

    // one pipeline step: L0 gates / c0 reload / rec1 dot / L1 gates /
    // c1 reload / W0 rotate / tail dots. TOKN3 = next staged token.
#define ITER(TOKN3_EXPR)                                                      \
    {                                                                         \
        const float pf = W0[tokn2 * H3 + col];                                \
        const int tokn3 = (TOKN3_EXPR);                                       \
        GATES(xw_cur, rec0, h0);                                              \
        if (home) h0buf[j] = h0;                                              \
        LDSFENCE();                                                           \
        _Pragma("unroll")                                                     \
        for (int q = 0; q < 5; ++q) c0[q] = h0q[q];                           \
        DOT2();                                                               \
        GATES(xw1, rec1, h1);                                                 \
        if (home) h1buf[j] = h1;                                              \
        LDSFENCE();                                                           \
        _Pragma("unroll")                                                     \
        for (int q = 0; q < 5; ++q) c1[q] = h1q[q];                           \
        xw_cur = fmaf(xw_nxt, gsc, bi0); xw_nxt = pf; tokn2 = tokn3;          \
        DOT01();                                                              \
    }

    // ---- prologue: L0 for t=0 (h0_{-1}=0 -> rec0 = br0); c1 = zeros ----
    {
        const float pf = W0[tokn2 * H3 + col];
        const int tokn3 = __builtin_amdgcn_readlane(tokA, 3);
        GATES(xw_cur, br0, h0);
        if (home) h0buf[j] = h0;
        LDSFENCE();
#pragma unroll
        for (int q = 0; q < 5; ++q) { c0[q] = h0q[q]; c1[q] = h1q[q]; }
        xw_cur = fmaf(xw_nxt, gsc, bi0); xw_nxt = pf; tokn2 = tokn3;
        DOT01();                                         // rec0/xw1 for i=1
    }

    // ---- main loops, split at the tokA/tokB boundary (no cmp/cndmask) ----
#pragma unroll 2
    for (int i = 1; i <= 60; ++i)                        // t3 = i+3 in 4..63
        ITER(__builtin_amdgcn_readlane(tokA, i + 3));
#pragma unroll 2
    for (int i = 61; i <= 124; ++i)                      // t3-64 = i-61 in 0..63
        ITER(__builtin_amdgcn_readlane(tokB, i - 61));
    for (int i = 125; i < TT; ++i)                       // t3 clamps to 127
        ITER(__builtin_amdgcn_readlane(tokB, 63));

    // ---- epilogue: L1 for t=127 (xw1 carried; rec1 from final c1) ----
    {
        DOT2();
        GATES(xw1, rec1, h1);
        if (home) h1buf[j] = h1;                         // final h1
        LDSFENCE();
    }

    // ---- dense (h1 @ Wd + bd) + softmax, lanes 0..14 ----
    const int l = lane < LL ? lane : LL - 1;
    float acc = bd[l];
#pragma unroll
    for (int k = 0; k < HH; ++k)
        acc = fmaf(h1buf[k], Wd[k * LL + l], acc);       // LDS broadcast reads

    float m = acc;
#pragma unroll
    for (int i = 0; i < LL; ++i) m = fmaxf(m, bclane(acc, i));
    const float e = __expf(acc - m);
    float s = 0.f;
#pragma unroll
    for (int i = 0; i < LL; ++i) s += bclane(e, i);
    const float pr = e * fast_rcp(s);

    if (lane < LL) out[b * LL + lane] = pr;
}

extern "C" void kernel_launch(void* const* d_in, const int* in_sizes, int n_in,
                              void* d_out, int out_size, void* d_ws, size_t ws_size,
                              hipStream_t stream) {
    const int*   x   = (const int*)  d_in[0];
    const float* W0  = (const float*)d_in[1];
    const float* U0  = (const float*)d_in[2];
    const float* b0i = (const float*)d_in[3];
    const float* b0r = (const float*)d_in[4];
    const float* W1  = (const float*)d_in[5];
    const float* U1  = (const float*)d_in[6];
    const float* b1i = (const float*)d_in[7];
    const float* b1r = (const float*)d_in[8];
    const float* Wd  = (const float*)d_in[9];
    const float* bd  = (const float*)d_in[10];
    // d_in[11] = drop_rate (identity), unused
    float* out = (float*)d_out;

    // 1 batch/wave, 4 waves/block -> 512 blocks = 2 blocks/CU = 2 waves/SIMD.
    dim3 grid(BB / 4), block(256);
    hipLaunchKernelGGL(gru2_kernel, grid, block, 0, stream,
                       x, W0, U0, b0i, b0r, W1, U1, b1i, b1r, Wd, bd, out);
}